// Round 1
// baseline (316.925 us; speedup 1.0000x reference)
//
#include <hip/hip_runtime.h>
#include <math.h>

#define C_IN 256
#define P_CH 64
#define H_IMG 128
#define W_IMG 128
#define HW (H_IMG*W_IMG)
#define N_IMG 4
#define K_PROTO 8
#define BN_EPS 1e-5f

// workspace layout (float offsets)
#define OFF_WT     0                     // 16384: W^T[c][p] with BN scale folded
#define OFF_BIASA  16384                 // 64: folded BN shift for conv1
#define OFF_PNORM  16448                 // 8: |proto_k|^2
#define OFF_MINMAX 16456                 // 8 uints: per-image (min,max) bits
#define OFF_H      16464                 // 4*64*16384 = 4194304: hidden activations
#define OFF_MD     (16464 + 4194304)     // 65536: min_dist per pixel
#define OFF_ATTN   (OFF_MD + 65536)      // 65536: attention map
// total = 4341840 floats = ~16.6 MB

__device__ __forceinline__ float silu_f(float x) { return x / (1.f + __expf(-x)); }

// ---------------- prep: fold BN into conv1 weights, proto norms, minmax init --
__global__ void prep_kernel(const float* __restrict__ w1, const float* __restrict__ bn1,
                            const float* __restrict__ protos, float* __restrict__ ws)
{
    int tid = threadIdx.x;
    for (int idx = tid; idx < 16384; idx += 256) {
        int c = idx >> 6, p = idx & 63;
        float sc = bn1[p] * rsqrtf(bn1[192 + p] + BN_EPS);
        ws[OFF_WT + idx] = w1[p * C_IN + c] * sc;
    }
    if (tid < 64) {
        float sc = bn1[tid] * rsqrtf(bn1[192 + tid] + BN_EPS);
        ws[OFF_BIASA + tid] = bn1[64 + tid] - bn1[128 + tid] * sc;
    }
    if (tid < 8) {
        float s = 0.f;
        for (int p = 0; p < 64; ++p) { float v = protos[tid * 64 + p]; s += v * v; }
        ws[OFF_PNORM + tid] = s;
    }
    if (tid < 4) {
        unsigned* mm = (unsigned*)(ws + OFF_MINMAX);
        mm[tid * 2]     = 0x7f7fffffu;  // FLT_MAX bits
        mm[tid * 2 + 1] = 0u;           // 0.0f bits
    }
}

// ---------------- A: 1x1 conv (256->64) + BN + SiLU ---------------------------
// one thread = one pixel, 64 fp32 accumulators; W read via uniform (scalar) loads
__global__ __launch_bounds__(256) void conv1x1_kernel(
    const float* __restrict__ x, const float* __restrict__ wt,
    const float* __restrict__ bias, float* __restrict__ h)
{
    int img = blockIdx.x >> 6;
    int pix = ((blockIdx.x & 63) << 8) + threadIdx.x;
    const float* xp = x + (size_t)img * C_IN * HW + pix;

    float acc[P_CH];
#pragma unroll
    for (int p = 0; p < P_CH; ++p) acc[p] = 0.f;

    for (int c = 0; c < C_IN; c += 4) {
        float x0 = xp[(size_t)c * HW];
        float x1 = xp[(size_t)(c + 1) * HW];
        float x2 = xp[(size_t)(c + 2) * HW];
        float x3 = xp[(size_t)(c + 3) * HW];
        const float* w0 = wt + c * 64;   // uniform across lanes -> s_load
#pragma unroll
        for (int p = 0; p < P_CH; ++p) {
            float a = acc[p];
            a = fmaf(x0, w0[p], a);
            a = fmaf(x1, w0[64 + p], a);
            a = fmaf(x2, w0[128 + p], a);
            a = fmaf(x3, w0[192 + p], a);
            acc[p] = a;
        }
    }
    float* hp = h + (size_t)img * P_CH * HW + pix;
#pragma unroll
    for (int p = 0; p < P_CH; ++p)
        hp[(size_t)p * HW] = silu_f(acc[p] + bias[p]);
}

// ---------------- B: DW3x3 + BN + SiLU fused with proto-distance -------------
__global__ __launch_bounds__(256) void dwconv_dev_kernel(
    const float* __restrict__ h, const float* __restrict__ dw,
    const float* __restrict__ bn2, const float* __restrict__ protos,
    const float* __restrict__ pnorm, float* __restrict__ md,
    unsigned* __restrict__ minmax)
{
    __shared__ float tile[18 * 18];
    __shared__ float red[512];
    int img = blockIdx.x >> 6;
    int t = blockIdx.x & 63;
    int y0 = (t >> 3) << 4, x0 = (t & 7) << 4;
    int tid = threadIdx.x;
    int ty = tid >> 4, tx = tid & 15;

    float norm2 = 0.f;
    float dot[K_PROTO];
#pragma unroll
    for (int k = 0; k < K_PROTO; ++k) dot[k] = 0.f;

    const float* himg = h + (size_t)img * P_CH * HW;
    for (int ch = 0; ch < P_CH; ++ch) {
        const float* hc = himg + (size_t)ch * HW;
        for (int l = tid; l < 324; l += 256) {
            int ly = l / 18, lx = l - ly * 18;
            int yy = y0 - 1 + ly, xx = x0 - 1 + lx;
            float v = 0.f;
            if (yy >= 0 && yy < H_IMG && xx >= 0 && xx < W_IMG)
                v = hc[yy * W_IMG + xx];
            tile[l] = v;
        }
        __syncthreads();
        float s = 0.f;
        const float* wch = dw + ch * 9;   // uniform -> scalar loads
#pragma unroll
        for (int dy = 0; dy < 3; ++dy)
#pragma unroll
            for (int dx = 0; dx < 3; ++dx)
                s = fmaf(tile[(ty + dy) * 18 + tx + dx], wch[dy * 3 + dx], s);
        float g = bn2[ch], bb = bn2[64 + ch], m = bn2[128 + ch], vv = bn2[192 + ch];
        float sc = g * rsqrtf(vv + BN_EPS);
        float val = silu_f(sc * s + (bb - m * sc));
        norm2 = fmaf(val, val, norm2);
#pragma unroll
        for (int k = 0; k < K_PROTO; ++k)
            dot[k] = fmaf(val, protos[k * 64 + ch], dot[k]);
        __syncthreads();
    }

    float d2min = 1e30f;
#pragma unroll
    for (int k = 0; k < K_PROTO; ++k)
        d2min = fminf(d2min, norm2 + pnorm[k] - 2.f * dot[k]);
    float mdv = sqrtf(fmaxf(d2min, 0.f)) * (1.f / 1.000001f);
    md[img * HW + (y0 + ty) * W_IMG + (x0 + tx)] = mdv;

    red[tid] = mdv; red[256 + tid] = mdv;
    __syncthreads();
    for (int s2 = 128; s2 > 0; s2 >>= 1) {
        if (tid < s2) {
            red[tid]       = fminf(red[tid], red[tid + s2]);
            red[256 + tid] = fmaxf(red[256 + tid], red[256 + tid + s2]);
        }
        __syncthreads();
    }
    if (tid == 0) {
        atomicMin(&minmax[img * 2],     __float_as_uint(red[0]));
        atomicMax(&minmax[img * 2 + 1], __float_as_uint(red[256]));
    }
}

// ---------------- C: normalize deviation + dual DS-conv attention ------------
__global__ __launch_bounds__(256) void attn_kernel(
    const float* __restrict__ md, const unsigned* __restrict__ minmax,
    const float* __restrict__ bs_dw, const float* __restrict__ bs_bn1,
    const float* __restrict__ bs_pw, const float* __restrict__ bs_bn2,
    const float* __restrict__ bl_dw, const float* __restrict__ bl_bn1,
    const float* __restrict__ bl_pw, const float* __restrict__ bl_bn2,
    const float* __restrict__ fuse_w, const float* __restrict__ fuse_b,
    float* __restrict__ attn)
{
    __shared__ float tile[20 * 20];
    int img = blockIdx.x >> 6;
    int t = blockIdx.x & 63;
    int y0 = (t >> 3) << 4, x0 = (t & 7) << 4;
    int tid = threadIdx.x;
    int ty = tid >> 4, tx = tid & 15;

    float fdmin = __uint_as_float(minmax[img * 2]);
    float fdmax = __uint_as_float(minmax[img * 2 + 1]);
    float inv = 1.f / (fdmax - fdmin + 1e-6f);

    const float* mdi = md + img * HW;
    for (int l = tid; l < 400; l += 256) {
        int ly = l / 20, lx = l - ly * 20;
        int yy = y0 - 2 + ly, xx = x0 - 2 + lx;
        float v = 0.f;   // zero padding on the deviation map
        if (yy >= 0 && yy < H_IMG && xx >= 0 && xx < W_IMG)
            v = (mdi[yy * W_IMG + xx] - fdmin) * inv;
        tile[l] = v;
    }
    __syncthreads();

    float c3 = 0.f;
#pragma unroll
    for (int dy = 0; dy < 3; ++dy)
#pragma unroll
        for (int dx = 0; dx < 3; ++dx)
            c3 = fmaf(tile[(ty + 1 + dy) * 20 + tx + 1 + dx], bs_dw[dy * 3 + dx], c3);
    float c5 = 0.f;
#pragma unroll
    for (int dy = 0; dy < 5; ++dy)
#pragma unroll
        for (int dx = 0; dx < 5; ++dx)
            c5 = fmaf(tile[(ty + dy) * 20 + tx + dx], bl_dw[dy * 5 + dx], c5);

    float s1 = bs_bn1[0] * rsqrtf(bs_bn1[3] + BN_EPS);
    float t1 = silu_f(s1 * c3 + (bs_bn1[1] - bs_bn1[2] * s1));
    float s2 = bl_bn1[0] * rsqrtf(bl_bn1[3] + BN_EPS);
    float t2 = silu_f(s2 * c5 + (bl_bn1[1] - bl_bn1[2] * s2));

    float acc = fuse_b[0];
#pragma unroll
    for (int c = 0; c < 8; ++c) {
        float scs = bs_bn2[c] * rsqrtf(bs_bn2[24 + c] + BN_EPS);
        float u1 = silu_f(scs * (bs_pw[c] * t1) + (bs_bn2[8 + c] - bs_bn2[16 + c] * scs));
        acc = fmaf(fuse_w[c], u1, acc);
        float scl = bl_bn2[c] * rsqrtf(bl_bn2[24 + c] + BN_EPS);
        float u2 = silu_f(scl * (bl_pw[c] * t2) + (bl_bn2[8 + c] - bl_bn2[16 + c] * scl));
        acc = fmaf(fuse_w[8 + c], u2, acc);
    }
    float a = 1.f / (1.f + __expf(-acc));
    attn[img * HW + (y0 + ty) * W_IMG + (x0 + tx)] = a;
}

// ---------------- D: out = x * (1 + gamma * attn) ----------------------------
__global__ __launch_bounds__(256) void final_kernel(
    const float* __restrict__ x, const float* __restrict__ attn,
    const float* __restrict__ gamma, float* __restrict__ out)
{
    size_t i = ((size_t)blockIdx.x * 256 + (size_t)threadIdx.x) * 4;
    float g = gamma[0];
    int b = (int)(i / ((size_t)C_IN * HW));
    int hw = (int)(i % HW);
    const float4 xv = *(const float4*)(x + i);
    const float4 av = *(const float4*)(attn + (size_t)b * HW + hw);
    float4 o;
    o.x = xv.x * (1.f + g * av.x);
    o.y = xv.y * (1.f + g * av.y);
    o.z = xv.z * (1.f + g * av.z);
    o.w = xv.w * (1.f + g * av.w);
    *(float4*)(out + i) = o;
}

extern "C" void kernel_launch(void* const* d_in, const int* in_sizes, int n_in,
                              void* d_out, int out_size, void* d_ws, size_t ws_size,
                              hipStream_t stream) {
    const float* x      = (const float*)d_in[0];
    const float* fp_w1  = (const float*)d_in[1];
    const float* fp_bn1 = (const float*)d_in[2];
    const float* fp_dw  = (const float*)d_in[3];
    const float* fp_bn2 = (const float*)d_in[4];
    const float* protos = (const float*)d_in[5];
    const float* bs_dw  = (const float*)d_in[6];
    const float* bs_bn1 = (const float*)d_in[7];
    const float* bs_pw  = (const float*)d_in[8];
    const float* bs_bn2 = (const float*)d_in[9];
    const float* bl_dw  = (const float*)d_in[10];
    const float* bl_bn1 = (const float*)d_in[11];
    const float* bl_pw  = (const float*)d_in[12];
    const float* bl_bn2 = (const float*)d_in[13];
    const float* fuse_w = (const float*)d_in[14];
    const float* fuse_b = (const float*)d_in[15];
    const float* gamma  = (const float*)d_in[16];
    float* ws  = (float*)d_ws;
    float* out = (float*)d_out;

    prep_kernel<<<1, 256, 0, stream>>>(fp_w1, fp_bn1, protos, ws);
    conv1x1_kernel<<<256, 256, 0, stream>>>(x, ws + OFF_WT, ws + OFF_BIASA, ws + OFF_H);
    dwconv_dev_kernel<<<256, 256, 0, stream>>>(ws + OFF_H, fp_dw, fp_bn2, protos,
                                               ws + OFF_PNORM, ws + OFF_MD,
                                               (unsigned*)(ws + OFF_MINMAX));
    attn_kernel<<<256, 256, 0, stream>>>(ws + OFF_MD, (const unsigned*)(ws + OFF_MINMAX),
                                         bs_dw, bs_bn1, bs_pw, bs_bn2,
                                         bl_dw, bl_bn1, bl_pw, bl_bn2,
                                         fuse_w, fuse_b, ws + OFF_ATTN);
    final_kernel<<<16384, 256, 0, stream>>>(x, ws + OFF_ATTN, gamma, out);
}

// Round 2
// 225.221 us; speedup vs baseline: 1.4072x; 1.4072x over previous
//
#include <hip/hip_runtime.h>
#include <math.h>

#define C_IN 256
#define P_CH 64
#define H_IMG 128
#define W_IMG 128
#define HW (H_IMG*W_IMG)
#define N_IMG 4
#define K_PROTO 8
#define BN_EPS 1e-5f

// workspace layout (float offsets)
#define OFF_WT     0                     // 16384: W^T[c][p] with BN scale folded
#define OFF_BIASA  16384                 // 64: folded BN shift for conv1
#define OFF_PNORM  16448                 // 8: |proto_k|^2
#define OFF_MINMAX 16456                 // 8 uints: per-image (min,max) bits
#define OFF_H      16464                 // 4*64*16384 = 4194304: hidden activations
#define OFF_MD     (16464 + 4194304)     // 65536: min_dist per pixel
#define OFF_ATTN   (OFF_MD + 65536)      // 65536: attention map

__device__ __forceinline__ float silu_f(float x) { return x / (1.f + __expf(-x)); }

// ---------------- prep: fold BN into conv1 weights, proto norms, minmax init --
// grid = 65 blocks (was 1 — serial single-block kernel)
__global__ void prep_kernel(const float* __restrict__ w1, const float* __restrict__ bn1,
                            const float* __restrict__ protos, float* __restrict__ ws)
{
    int bx = blockIdx.x, tid = threadIdx.x;
    if (bx < 64) {
        int idx = bx * 256 + tid;
        int c = idx >> 6, p = idx & 63;
        float sc = bn1[p] * rsqrtf(bn1[192 + p] + BN_EPS);
        ws[OFF_WT + idx] = w1[p * C_IN + c] * sc;
    } else {
        if (tid < 64) {
            float sc = bn1[tid] * rsqrtf(bn1[192 + tid] + BN_EPS);
            ws[OFF_BIASA + tid] = bn1[64 + tid] - bn1[128 + tid] * sc;
        }
        if (tid < 8) {
            float s = 0.f;
            for (int p = 0; p < 64; ++p) { float v = protos[tid * 64 + p]; s += v * v; }
            ws[OFF_PNORM + tid] = s;
        }
        if (tid < 4) {
            unsigned* mm = (unsigned*)(ws + OFF_MINMAX);
            mm[tid * 2]     = 0x7f7fffffu;  // FLT_MAX bits
            mm[tid * 2 + 1] = 0u;           // 0.0f bits
        }
    }
}

// ---------------- A: 1x1 conv (256->64) + BN + SiLU ---------------------------
// Block = one image row (128 px) x 64 p. Thread = 2 px x 16 p = 32 acc.
// x staged to LDS (register-prefetch dbuf, 1 barrier/chunk); W via uniform s_loads.
__global__ __launch_bounds__(256, 2) void conv1x1_kernel(
    const float* __restrict__ x, const float* __restrict__ wt,
    const float* __restrict__ bias, float* __restrict__ h)
{
    __shared__ float xs[2][8][128];
    int bx = blockIdx.x;
    int img = bx >> 7;
    int row = bx & 127;
    int tid = threadIdx.x;
    int pgrp = tid >> 6;           // 0..3 — constant within a wave
    int lane = tid & 63;
    int sc_ = tid >> 5;            // staging: channel-in-chunk 0..7
    int sp_ = (tid & 31) * 4;      // staging: pixel*4

    const float* xbase = x + (size_t)img * C_IN * HW + row * W_IMG;
    float* hb = h + (size_t)img * P_CH * HW + row * W_IMG;

    float a0[16], a1[16];
#pragma unroll
    for (int j = 0; j < 16; ++j) { a0[j] = 0.f; a1[j] = 0.f; }

    // prologue: stage chunk 0
    {
        float4 f0 = *(const float4*)(xbase + (size_t)sc_ * HW + sp_);
        *(float4*)&xs[0][sc_][sp_] = f0;
    }
    __syncthreads();

    for (int k = 0; k < 32; ++k) {
        float4 nxt;
        if (k < 31)
            nxt = *(const float4*)(xbase + (size_t)((k + 1) * 8 + sc_) * HW + sp_);

        const float (*xb)[128] = xs[k & 1];
        int c0 = k * 8;
#pragma unroll
        for (int cl = 0; cl < 8; ++cl) {
            float xv0 = xb[cl][lane];
            float xv1 = xb[cl][lane + 64];
            int wof = __builtin_amdgcn_readfirstlane((c0 + cl) * 64 + pgrp * 16);
            const float* w = wt + wof;
#pragma unroll
            for (int j = 0; j < 16; ++j) {
                a0[j] = fmaf(xv0, w[j], a0[j]);
                a1[j] = fmaf(xv1, w[j], a1[j]);
            }
        }
        if (k < 31)
            *(float4*)&xs[(k + 1) & 1][sc_][sp_] = nxt;
        __syncthreads();
    }

    int bof = __builtin_amdgcn_readfirstlane(pgrp * 16);
#pragma unroll
    for (int j = 0; j < 16; ++j) {
        int p = bof + j;
        float bb = bias[p];
        hb[(size_t)p * HW + lane]      = silu_f(a0[j] + bb);
        hb[(size_t)p * HW + lane + 64] = silu_f(a1[j] + bb);
    }
}

// ---------------- B: DW3x3 + BN + SiLU fused with proto-distance -------------
// 8-channel chunks, register-prefetch double-buffered LDS, 1 barrier/chunk.
__global__ __launch_bounds__(256) void dwconv_dev_kernel(
    const float* __restrict__ h, const float* __restrict__ dw,
    const float* __restrict__ bn2, const float* __restrict__ protos,
    const float* __restrict__ pnorm, float* __restrict__ md,
    unsigned* __restrict__ minmax)
{
    __shared__ float tile[2][8 * 324];
    __shared__ float red[512];
    int img = blockIdx.x >> 6;
    int t = blockIdx.x & 63;
    int y0 = (t >> 3) << 4, x0 = (t & 7) << 4;
    int tid = threadIdx.x;
    int ty = tid >> 4, tx = tid & 15;

    const float* himg = h + (size_t)img * P_CH * HW;

    // precompute staging slots: 8*324 = 2592 elements, 11 rounds of 256
    int  pre_off[11];   // cl*HW + yy*128+xx (0 if OOB)
    bool pre_ok[11];    // in image bounds
    bool pre_v[11];     // slot < 2592
#pragma unroll
    for (int r = 0; r < 11; ++r) {
        int l = tid + r * 256;
        bool valid = l < 2592;
        int cl = l / 324;
        int rr = l - cl * 324;
        int ly = rr / 18, lx = rr - ly * 18;
        int yy = y0 - 1 + ly, xx = x0 - 1 + lx;
        bool inb = (yy >= 0) & (yy < H_IMG) & (xx >= 0) & (xx < W_IMG);
        pre_v[r] = valid;
        pre_ok[r] = valid && inb;
        pre_off[r] = cl * HW + (inb ? (yy * W_IMG + xx) : 0);
    }

    float norm2 = 0.f;
    float dot[K_PROTO];
#pragma unroll
    for (int k = 0; k < K_PROTO; ++k) dot[k] = 0.f;

    // prologue: stage chunk 0
    {
#pragma unroll
        for (int r = 0; r < 11; ++r) {
            float v = pre_ok[r] ? himg[pre_off[r]] : 0.f;
            if (pre_v[r]) tile[0][tid + r * 256] = v;
        }
    }
    __syncthreads();

    for (int k = 0; k < 8; ++k) {
        float pf[11];
        if (k < 7) {
            const float* hs = himg + (size_t)(k + 1) * 8 * HW;
#pragma unroll
            for (int r = 0; r < 11; ++r)
                pf[r] = pre_ok[r] ? hs[pre_off[r]] : 0.f;
        }

        const float* tb = tile[k & 1];
        int c0 = k * 8;
#pragma unroll
        for (int cl = 0; cl < 8; ++cl) {
            int ch = c0 + cl;
            const float* tc = tb + cl * 324;
            const float* wch = dw + ch * 9;   // uniform -> s_load
            float s = 0.f;
#pragma unroll
            for (int dy = 0; dy < 3; ++dy)
#pragma unroll
                for (int dx = 0; dx < 3; ++dx)
                    s = fmaf(tc[(ty + dy) * 18 + tx + dx], wch[dy * 3 + dx], s);
            float g = bn2[ch], bb = bn2[64 + ch], m = bn2[128 + ch], vv = bn2[192 + ch];
            float scale = g * rsqrtf(vv + BN_EPS);
            float val = silu_f(scale * s + (bb - m * scale));
            norm2 = fmaf(val, val, norm2);
#pragma unroll
            for (int kk = 0; kk < K_PROTO; ++kk)
                dot[kk] = fmaf(val, protos[kk * 64 + ch], dot[kk]);
        }

        if (k < 7) {
            float* tn = tile[(k + 1) & 1];
#pragma unroll
            for (int r = 0; r < 11; ++r)
                if (pre_v[r]) tn[tid + r * 256] = pf[r];
        }
        __syncthreads();
    }

    float d2min = 1e30f;
#pragma unroll
    for (int k = 0; k < K_PROTO; ++k)
        d2min = fminf(d2min, norm2 + pnorm[k] - 2.f * dot[k]);
    float mdv = sqrtf(fmaxf(d2min, 0.f)) * (1.f / 1.000001f);
    md[img * HW + (y0 + ty) * W_IMG + (x0 + tx)] = mdv;

    red[tid] = mdv; red[256 + tid] = mdv;
    __syncthreads();
    for (int s2 = 128; s2 > 0; s2 >>= 1) {
        if (tid < s2) {
            red[tid]       = fminf(red[tid], red[tid + s2]);
            red[256 + tid] = fmaxf(red[256 + tid], red[256 + tid + s2]);
        }
        __syncthreads();
    }
    if (tid == 0) {
        atomicMin(&minmax[img * 2],     __float_as_uint(red[0]));
        atomicMax(&minmax[img * 2 + 1], __float_as_uint(red[256]));
    }
}

// ---------------- C: normalize deviation + dual DS-conv attention ------------
__global__ __launch_bounds__(256) void attn_kernel(
    const float* __restrict__ md, const unsigned* __restrict__ minmax,
    const float* __restrict__ bs_dw, const float* __restrict__ bs_bn1,
    const float* __restrict__ bs_pw, const float* __restrict__ bs_bn2,
    const float* __restrict__ bl_dw, const float* __restrict__ bl_bn1,
    const float* __restrict__ bl_pw, const float* __restrict__ bl_bn2,
    const float* __restrict__ fuse_w, const float* __restrict__ fuse_b,
    float* __restrict__ attn)
{
    __shared__ float tile[20 * 20];
    int img = blockIdx.x >> 6;
    int t = blockIdx.x & 63;
    int y0 = (t >> 3) << 4, x0 = (t & 7) << 4;
    int tid = threadIdx.x;
    int ty = tid >> 4, tx = tid & 15;

    float fdmin = __uint_as_float(minmax[img * 2]);
    float fdmax = __uint_as_float(minmax[img * 2 + 1]);
    float inv = 1.f / (fdmax - fdmin + 1e-6f);

    const float* mdi = md + img * HW;
    for (int l = tid; l < 400; l += 256) {
        int ly = l / 20, lx = l - ly * 20;
        int yy = y0 - 2 + ly, xx = x0 - 2 + lx;
        float v = 0.f;
        if (yy >= 0 && yy < H_IMG && xx >= 0 && xx < W_IMG)
            v = (mdi[yy * W_IMG + xx] - fdmin) * inv;
        tile[l] = v;
    }
    __syncthreads();

    float c3 = 0.f;
#pragma unroll
    for (int dy = 0; dy < 3; ++dy)
#pragma unroll
        for (int dx = 0; dx < 3; ++dx)
            c3 = fmaf(tile[(ty + 1 + dy) * 20 + tx + 1 + dx], bs_dw[dy * 3 + dx], c3);
    float c5 = 0.f;
#pragma unroll
    for (int dy = 0; dy < 5; ++dy)
#pragma unroll
        for (int dx = 0; dx < 5; ++dx)
            c5 = fmaf(tile[(ty + dy) * 20 + tx + dx], bl_dw[dy * 5 + dx], c5);

    float s1 = bs_bn1[0] * rsqrtf(bs_bn1[3] + BN_EPS);
    float t1 = silu_f(s1 * c3 + (bs_bn1[1] - bs_bn1[2] * s1));
    float s2 = bl_bn1[0] * rsqrtf(bl_bn1[3] + BN_EPS);
    float t2 = silu_f(s2 * c5 + (bl_bn1[1] - bl_bn1[2] * s2));

    float acc = fuse_b[0];
#pragma unroll
    for (int c = 0; c < 8; ++c) {
        float scs = bs_bn2[c] * rsqrtf(bs_bn2[24 + c] + BN_EPS);
        float u1 = silu_f(scs * (bs_pw[c] * t1) + (bs_bn2[8 + c] - bs_bn2[16 + c] * scs));
        acc = fmaf(fuse_w[c], u1, acc);
        float scl = bl_bn2[c] * rsqrtf(bl_bn2[24 + c] + BN_EPS);
        float u2 = silu_f(scl * (bl_pw[c] * t2) + (bl_bn2[8 + c] - bl_bn2[16 + c] * scl));
        acc = fmaf(fuse_w[8 + c], u2, acc);
    }
    float a = 1.f / (1.f + __expf(-acc));
    attn[img * HW + (y0 + ty) * W_IMG + (x0 + tx)] = a;
}

// ---------------- D: out = x * (1 + gamma * attn) ----------------------------
__global__ __launch_bounds__(256) void final_kernel(
    const float* __restrict__ x, const float* __restrict__ attn,
    const float* __restrict__ gamma, float* __restrict__ out)
{
    size_t i = ((size_t)blockIdx.x * 256 + (size_t)threadIdx.x) * 4;
    float g = gamma[0];
    int b = (int)(i / ((size_t)C_IN * HW));
    int hw = (int)(i % HW);
    const float4 xv = *(const float4*)(x + i);
    const float4 av = *(const float4*)(attn + (size_t)b * HW + hw);
    float4 o;
    o.x = xv.x * (1.f + g * av.x);
    o.y = xv.y * (1.f + g * av.y);
    o.z = xv.z * (1.f + g * av.z);
    o.w = xv.w * (1.f + g * av.w);
    *(float4*)(out + i) = o;
}

extern "C" void kernel_launch(void* const* d_in, const int* in_sizes, int n_in,
                              void* d_out, int out_size, void* d_ws, size_t ws_size,
                              hipStream_t stream) {
    const float* x      = (const float*)d_in[0];
    const float* fp_w1  = (const float*)d_in[1];
    const float* fp_bn1 = (const float*)d_in[2];
    const float* fp_dw  = (const float*)d_in[3];
    const float* fp_bn2 = (const float*)d_in[4];
    const float* protos = (const float*)d_in[5];
    const float* bs_dw  = (const float*)d_in[6];
    const float* bs_bn1 = (const float*)d_in[7];
    const float* bs_pw  = (const float*)d_in[8];
    const float* bs_bn2 = (const float*)d_in[9];
    const float* bl_dw  = (const float*)d_in[10];
    const float* bl_bn1 = (const float*)d_in[11];
    const float* bl_pw  = (const float*)d_in[12];
    const float* bl_bn2 = (const float*)d_in[13];
    const float* fuse_w = (const float*)d_in[14];
    const float* fuse_b = (const float*)d_in[15];
    const float* gamma  = (const float*)d_in[16];
    float* ws  = (float*)d_ws;
    float* out = (float*)d_out;

    prep_kernel<<<65, 256, 0, stream>>>(fp_w1, fp_bn1, protos, ws);
    conv1x1_kernel<<<512, 256, 0, stream>>>(x, ws + OFF_WT, ws + OFF_BIASA, ws + OFF_H);
    dwconv_dev_kernel<<<256, 256, 0, stream>>>(ws + OFF_H, fp_dw, fp_bn2, protos,
                                               ws + OFF_PNORM, ws + OFF_MD,
                                               (unsigned*)(ws + OFF_MINMAX));
    attn_kernel<<<256, 256, 0, stream>>>(ws + OFF_MD, (const unsigned*)(ws + OFF_MINMAX),
                                         bs_dw, bs_bn1, bs_pw, bs_bn2,
                                         bl_dw, bl_bn1, bl_pw, bl_bn2,
                                         fuse_w, fuse_b, ws + OFF_ATTN);
    final_kernel<<<16384, 256, 0, stream>>>(x, ws + OFF_ATTN, gamma, out);
}

// Round 3
// 220.514 us; speedup vs baseline: 1.4372x; 1.0213x over previous
//
#include <hip/hip_runtime.h>
#include <math.h>

#define C_IN 256
#define P_CH 64
#define H_IMG 128
#define W_IMG 128
#define HW (H_IMG*W_IMG)
#define N_IMG 4
#define K_PROTO 8
#define BN_EPS 1e-5f

// workspace layout (float offsets)
#define OFF_WT     0                     // 16384: W^T[c][p] with BN scale folded
#define OFF_BIASA  16384                 // 64: folded BN shift for conv1
#define OFF_PNORM  16448                 // 8: |proto_k|^2
#define OFF_MINMAX 16456                 // 8 uints: per-image (min,max) bits
#define OFF_H      16464                 // 4*64*16384 = 4194304: hidden activations
#define OFF_MD     (16464 + 4194304)     // 65536: min_dist per pixel
#define OFF_ATTN   (OFF_MD + 65536)      // 65536: attention map

__device__ __forceinline__ float silu_f(float x) { return x / (1.f + __expf(-x)); }

// ---------------- prep: fold BN into conv1 weights, proto norms, minmax init --
__global__ void prep_kernel(const float* __restrict__ w1, const float* __restrict__ bn1,
                            const float* __restrict__ protos, float* __restrict__ ws)
{
    int bx = blockIdx.x, tid = threadIdx.x;
    if (bx < 64) {
        int idx = bx * 256 + tid;
        int c = idx >> 6, p = idx & 63;
        float sc = bn1[p] * rsqrtf(bn1[192 + p] + BN_EPS);
        ws[OFF_WT + idx] = w1[p * C_IN + c] * sc;
    } else {
        if (tid < 64) {
            float sc = bn1[tid] * rsqrtf(bn1[192 + tid] + BN_EPS);
            ws[OFF_BIASA + tid] = bn1[64 + tid] - bn1[128 + tid] * sc;
        }
        if (tid < 8) {
            float s = 0.f;
            for (int p = 0; p < 64; ++p) { float v = protos[tid * 64 + p]; s += v * v; }
            ws[OFF_PNORM + tid] = s;
        }
        if (tid < 4) {
            unsigned* mm = (unsigned*)(ws + OFF_MINMAX);
            mm[tid * 2]     = 0x7f7fffffu;  // FLT_MAX bits
            mm[tid * 2 + 1] = 0u;           // 0.0f bits
        }
    }
}

// ---------------- A: 1x1 conv (256->64) + BN + SiLU ---------------------------
// Block = 64-px half-row x 64 p. Thread = 1 px x 16 p. Grid 1024 -> 4 blocks/CU.
__global__ __launch_bounds__(256, 4) void conv1x1_kernel(
    const float* __restrict__ x, const float* __restrict__ wt,
    const float* __restrict__ bias, float* __restrict__ h)
{
    __shared__ float xs[2][8][64];
    int bx = blockIdx.x;
    int img = bx >> 8;
    int rem = bx & 255;
    int row = rem >> 1;
    int half = rem & 1;
    int tid = threadIdx.x;
    int pgrp = tid >> 6;           // 0..3, wave-uniform
    int lane = tid & 63;
    int sc_ = tid >> 4;            // staging (t<128): channel-in-chunk 0..7
    int sp_ = (tid & 15) * 4;      // staging: pixel*4

    const float* xbase = x + (size_t)img * C_IN * HW + row * W_IMG + half * 64;
    float* hb = h + (size_t)img * P_CH * HW + row * W_IMG + half * 64;

    float acc[16];
#pragma unroll
    for (int j = 0; j < 16; ++j) acc[j] = 0.f;

    if (tid < 128)
        *(float4*)&xs[0][sc_][sp_] = *(const float4*)(xbase + (size_t)sc_ * HW + sp_);
    __syncthreads();

    for (int k = 0; k < 32; ++k) {
        float4 nxt;
        if (k < 31 && tid < 128)
            nxt = *(const float4*)(xbase + (size_t)((k + 1) * 8 + sc_) * HW + sp_);

        const float (*xb)[64] = xs[k & 1];
        int c0 = k * 8;
#pragma unroll
        for (int cl = 0; cl < 8; ++cl) {
            float xv = xb[cl][lane];
            int wof = __builtin_amdgcn_readfirstlane((c0 + cl) * 64 + pgrp * 16);
            const float* w = wt + wof;
#pragma unroll
            for (int j = 0; j < 16; ++j)
                acc[j] = fmaf(xv, w[j], acc[j]);
        }
        if (k < 31 && tid < 128)
            *(float4*)&xs[(k + 1) & 1][sc_][sp_] = nxt;
        __syncthreads();
    }

    int bof = __builtin_amdgcn_readfirstlane(pgrp * 16);
#pragma unroll
    for (int j = 0; j < 16; ++j) {
        int p = bof + j;
        hb[(size_t)p * HW + lane] = silu_f(acc[j] + bias[p]);
    }
}

// ---------------- B: DW3x3 + BN + SiLU fused with proto-distance -------------
// 1024 threads: quarter q (256 thr) handles channels [q*16, q*16+16) in 2 chunks
// of 8 (register prefetch). Partial (norm2, dot[8]) combined via LDS aliased
// onto the staging buffer. 16 waves/CU.
__global__ __launch_bounds__(1024) void dwconv_dev_kernel(
    const float* __restrict__ h, const float* __restrict__ dw,
    const float* __restrict__ bn2, const float* __restrict__ protos,
    const float* __restrict__ pnorm, float* __restrict__ md,
    unsigned* __restrict__ minmax)
{
    __shared__ float smem[4 * 8 * 324];   // 41472 B; also reused for partials
    int img = blockIdx.x >> 6;
    int t = blockIdx.x & 63;
    int y0 = (t >> 3) << 4, x0 = (t & 7) << 4;
    int tid = threadIdx.x;
    int q = tid >> 8;          // quarter 0..3
    int qtid = tid & 255;
    int ty = qtid >> 4, tx = qtid & 15;

    const float* himg = h + (size_t)img * P_CH * HW;
    float* qt = smem + q * (8 * 324);

    // precompute staging slots: 8*324 = 2592 elements, 11 rounds of 256
    int  pre_off[11];
    bool pre_ok[11];
    bool pre_v[11];
#pragma unroll
    for (int r = 0; r < 11; ++r) {
        int l = qtid + r * 256;
        bool valid = l < 2592;
        int cl = l / 324;
        int rr = l - cl * 324;
        int ly = rr / 18, lx = rr - ly * 18;
        int yy = y0 - 1 + ly, xx = x0 - 1 + lx;
        bool inb = (yy >= 0) & (yy < H_IMG) & (xx >= 0) & (xx < W_IMG);
        pre_v[r] = valid;
        pre_ok[r] = valid && inb;
        pre_off[r] = cl * HW + (inb ? (yy * W_IMG + xx) : 0);
    }

    float norm2 = 0.f;
    float dot[K_PROTO];
#pragma unroll
    for (int k = 0; k < K_PROTO; ++k) dot[k] = 0.f;

    // stage chunk 0 (channels q*16 .. q*16+7)
    {
        const float* hs = himg + (size_t)(q * 16) * HW;
#pragma unroll
        for (int r = 0; r < 11; ++r) {
            float v = pre_ok[r] ? hs[pre_off[r]] : 0.f;
            if (pre_v[r]) qt[qtid + r * 256] = v;
        }
    }
    __syncthreads();

    for (int k = 0; k < 2; ++k) {
        float pf[11];
        if (k == 0) {
            const float* hs = himg + (size_t)(q * 16 + 8) * HW;
#pragma unroll
            for (int r = 0; r < 11; ++r)
                pf[r] = pre_ok[r] ? hs[pre_off[r]] : 0.f;
        }

        int c0 = q * 16 + k * 8;
#pragma unroll
        for (int cl = 0; cl < 8; ++cl) {
            int ch = c0 + cl;
            const float* tc = qt + cl * 324;
            const float* wch = dw + ch * 9;   // uniform -> s_load
            float s = 0.f;
#pragma unroll
            for (int dy = 0; dy < 3; ++dy)
#pragma unroll
                for (int dx = 0; dx < 3; ++dx)
                    s = fmaf(tc[(ty + dy) * 18 + tx + dx], wch[dy * 3 + dx], s);
            float g = bn2[ch], bb = bn2[64 + ch], m = bn2[128 + ch], vv = bn2[192 + ch];
            float scale = g * rsqrtf(vv + BN_EPS);
            float val = silu_f(scale * s + (bb - m * scale));
            norm2 = fmaf(val, val, norm2);
#pragma unroll
            for (int kk = 0; kk < K_PROTO; ++kk)
                dot[kk] = fmaf(val, protos[kk * 64 + ch], dot[kk]);
        }

        if (k == 0) {
            __syncthreads();          // everyone done reading chunk 0
#pragma unroll
            for (int r = 0; r < 11; ++r)
                if (pre_v[r]) qt[qtid + r * 256] = pf[r];
            __syncthreads();
        }
    }
    __syncthreads();   // all quarters done reading tiles -> reuse smem

    // write partials: P[q][pix][9] (stride-9 -> 2-way LDS aliasing, free)
    float* P = smem;
    {
        float* dst = P + (q * 256 + qtid) * 9;
        dst[0] = norm2;
#pragma unroll
        for (int kk = 0; kk < K_PROTO; ++kk) dst[1 + kk] = dot[kk];
    }
    __syncthreads();

    float wmin = 1e30f, wmax = -1e30f, mdv = 0.f;
    if (q == 0) {
        float n2 = 0.f, dd[K_PROTO];
#pragma unroll
        for (int kk = 0; kk < K_PROTO; ++kk) dd[kk] = 0.f;
#pragma unroll
        for (int qq = 0; qq < 4; ++qq) {
            const float* src = P + (qq * 256 + qtid) * 9;
            n2 += src[0];
#pragma unroll
            for (int kk = 0; kk < K_PROTO; ++kk) dd[kk] += src[1 + kk];
        }
        float d2min = 1e30f;
#pragma unroll
        for (int kk = 0; kk < K_PROTO; ++kk)
            d2min = fminf(d2min, n2 + pnorm[kk] - 2.f * dd[kk]);
        mdv = sqrtf(fmaxf(d2min, 0.f)) * (1.f / 1.000001f);
        md[img * HW + (y0 + ty) * W_IMG + (x0 + tx)] = mdv;
        wmin = mdv; wmax = mdv;
        // wave-level min/max reduce (64 lanes)
#pragma unroll
        for (int d = 32; d > 0; d >>= 1) {
            wmin = fminf(wmin, __shfl_xor(wmin, d));
            wmax = fmaxf(wmax, __shfl_xor(wmax, d));
        }
    }
    __syncthreads();   // partial reads done -> reuse smem head
    if (q == 0 && (qtid & 63) == 0) {
        int wid = qtid >> 6;
        smem[wid * 2]     = wmin;
        smem[wid * 2 + 1] = wmax;
    }
    __syncthreads();
    if (tid == 0) {
        float bmin = fminf(fminf(smem[0], smem[2]), fminf(smem[4], smem[6]));
        float bmax = fmaxf(fmaxf(smem[1], smem[3]), fmaxf(smem[5], smem[7]));
        atomicMin(&minmax[img * 2],     __float_as_uint(bmin));
        atomicMax(&minmax[img * 2 + 1], __float_as_uint(bmax));
    }
}

// ---------------- C: normalize deviation + dual DS-conv attention ------------
__global__ __launch_bounds__(256) void attn_kernel(
    const float* __restrict__ md, const unsigned* __restrict__ minmax,
    const float* __restrict__ bs_dw, const float* __restrict__ bs_bn1,
    const float* __restrict__ bs_pw, const float* __restrict__ bs_bn2,
    const float* __restrict__ bl_dw, const float* __restrict__ bl_bn1,
    const float* __restrict__ bl_pw, const float* __restrict__ bl_bn2,
    const float* __restrict__ fuse_w, const float* __restrict__ fuse_b,
    float* __restrict__ attn)
{
    __shared__ float tile[20 * 20];
    int img = blockIdx.x >> 6;
    int t = blockIdx.x & 63;
    int y0 = (t >> 3) << 4, x0 = (t & 7) << 4;
    int tid = threadIdx.x;
    int ty = tid >> 4, tx = tid & 15;

    float fdmin = __uint_as_float(minmax[img * 2]);
    float fdmax = __uint_as_float(minmax[img * 2 + 1]);
    float inv = 1.f / (fdmax - fdmin + 1e-6f);

    const float* mdi = md + img * HW;
    for (int l = tid; l < 400; l += 256) {
        int ly = l / 20, lx = l - ly * 20;
        int yy = y0 - 2 + ly, xx = x0 - 2 + lx;
        float v = 0.f;
        if (yy >= 0 && yy < H_IMG && xx >= 0 && xx < W_IMG)
            v = (mdi[yy * W_IMG + xx] - fdmin) * inv;
        tile[l] = v;
    }
    __syncthreads();

    float c3 = 0.f;
#pragma unroll
    for (int dy = 0; dy < 3; ++dy)
#pragma unroll
        for (int dx = 0; dx < 3; ++dx)
            c3 = fmaf(tile[(ty + 1 + dy) * 20 + tx + 1 + dx], bs_dw[dy * 3 + dx], c3);
    float c5 = 0.f;
#pragma unroll
    for (int dy = 0; dy < 5; ++dy)
#pragma unroll
        for (int dx = 0; dx < 5; ++dx)
            c5 = fmaf(tile[(ty + dy) * 20 + tx + dx], bl_dw[dy * 5 + dx], c5);

    float s1 = bs_bn1[0] * rsqrtf(bs_bn1[3] + BN_EPS);
    float t1 = silu_f(s1 * c3 + (bs_bn1[1] - bs_bn1[2] * s1));
    float s2 = bl_bn1[0] * rsqrtf(bl_bn1[3] + BN_EPS);
    float t2 = silu_f(s2 * c5 + (bl_bn1[1] - bl_bn1[2] * s2));

    float acc = fuse_b[0];
#pragma unroll
    for (int c = 0; c < 8; ++c) {
        float scs = bs_bn2[c] * rsqrtf(bs_bn2[24 + c] + BN_EPS);
        float u1 = silu_f(scs * (bs_pw[c] * t1) + (bs_bn2[8 + c] - bs_bn2[16 + c] * scs));
        acc = fmaf(fuse_w[c], u1, acc);
        float scl = bl_bn2[c] * rsqrtf(bl_bn2[24 + c] + BN_EPS);
        float u2 = silu_f(scl * (bl_pw[c] * t2) + (bl_bn2[8 + c] - bl_bn2[16 + c] * scl));
        acc = fmaf(fuse_w[8 + c], u2, acc);
    }
    float a = 1.f / (1.f + __expf(-acc));
    attn[img * HW + (y0 + ty) * W_IMG + (x0 + tx)] = a;
}

// ---------------- D: out = x * (1 + gamma * attn) ----------------------------
__global__ __launch_bounds__(256) void final_kernel(
    const float* __restrict__ x, const float* __restrict__ attn,
    const float* __restrict__ gamma, float* __restrict__ out)
{
    size_t i = ((size_t)blockIdx.x * 256 + (size_t)threadIdx.x) * 4;
    float g = gamma[0];
    int b = (int)(i / ((size_t)C_IN * HW));
    int hw = (int)(i % HW);
    const float4 xv = *(const float4*)(x + i);
    const float4 av = *(const float4*)(attn + (size_t)b * HW + hw);
    float4 o;
    o.x = xv.x * (1.f + g * av.x);
    o.y = xv.y * (1.f + g * av.y);
    o.z = xv.z * (1.f + g * av.z);
    o.w = xv.w * (1.f + g * av.w);
    *(float4*)(out + i) = o;
}

extern "C" void kernel_launch(void* const* d_in, const int* in_sizes, int n_in,
                              void* d_out, int out_size, void* d_ws, size_t ws_size,
                              hipStream_t stream) {
    const float* x      = (const float*)d_in[0];
    const float* fp_w1  = (const float*)d_in[1];
    const float* fp_bn1 = (const float*)d_in[2];
    const float* fp_dw  = (const float*)d_in[3];
    const float* fp_bn2 = (const float*)d_in[4];
    const float* protos = (const float*)d_in[5];
    const float* bs_dw  = (const float*)d_in[6];
    const float* bs_bn1 = (const float*)d_in[7];
    const float* bs_pw  = (const float*)d_in[8];
    const float* bs_bn2 = (const float*)d_in[9];
    const float* bl_dw  = (const float*)d_in[10];
    const float* bl_bn1 = (const float*)d_in[11];
    const float* bl_pw  = (const float*)d_in[12];
    const float* bl_bn2 = (const float*)d_in[13];
    const float* fuse_w = (const float*)d_in[14];
    const float* fuse_b = (const float*)d_in[15];
    const float* gamma  = (const float*)d_in[16];
    float* ws  = (float*)d_ws;
    float* out = (float*)d_out;

    prep_kernel<<<65, 256, 0, stream>>>(fp_w1, fp_bn1, protos, ws);
    conv1x1_kernel<<<1024, 256, 0, stream>>>(x, ws + OFF_WT, ws + OFF_BIASA, ws + OFF_H);
    dwconv_dev_kernel<<<256, 1024, 0, stream>>>(ws + OFF_H, fp_dw, fp_bn2, protos,
                                                ws + OFF_PNORM, ws + OFF_MD,
                                                (unsigned*)(ws + OFF_MINMAX));
    attn_kernel<<<256, 256, 0, stream>>>(ws + OFF_MD, (const unsigned*)(ws + OFF_MINMAX),
                                         bs_dw, bs_bn1, bs_pw, bs_bn2,
                                         bl_dw, bl_bn1, bl_pw, bl_bn2,
                                         fuse_w, fuse_b, ws + OFF_ATTN);
    final_kernel<<<16384, 256, 0, stream>>>(x, ws + OFF_ATTN, gamma, out);
}

// Round 4
// 188.914 us; speedup vs baseline: 1.6776x; 1.1673x over previous
//
#include <hip/hip_runtime.h>
#include <math.h>

#define C_IN 256
#define P_CH 64
#define H_IMG 128
#define W_IMG 128
#define HW (H_IMG*W_IMG)
#define N_IMG 4
#define K_PROTO 8
#define BN_EPS 1e-5f

typedef unsigned short u16;
typedef __attribute__((ext_vector_type(4))) short bf16x4;
typedef __attribute__((ext_vector_type(8))) short bf16x8;
typedef __attribute__((ext_vector_type(4))) float f32x4;

// workspace layout (float offsets)
#define OFF_WTBF   0                     // 8192 fl = 16384 bf16: W bf16 [n][k], BN-folded
#define OFF_BIASA  8192                  // 64: folded BN shift
#define OFF_PNORM  8256                  // 8: |proto_k|^2
#define OFF_MINMAX 8264                  // 8 uints
#define OFF_H      8272                  // 4*64*16384 bf16 = 2097152 floats
#define OFF_MD     (8272 + 2097152)      // 65536
#define OFF_ATTN   (OFF_MD + 65536)      // 65536

__device__ __forceinline__ float silu_f(float x) { return x / (1.f + __expf(-x)); }

__device__ __forceinline__ u16 f2bf(float f) {   // round-to-nearest-even
    union { float f; unsigned u; } v; v.f = f;
    unsigned r = v.u + 0x7fffu + ((v.u >> 16) & 1u);
    return (u16)(r >> 16);
}
__device__ __forceinline__ float bf2f(u16 s) {
    union { unsigned u; float f; } v; v.u = ((unsigned)s) << 16; return v.f;
}

// ---------------- prep: fold BN into bf16 W [n][k], proto norms, minmax init --
__global__ void prep_kernel(const float* __restrict__ w1, const float* __restrict__ bn1,
                            const float* __restrict__ protos, float* __restrict__ ws)
{
    int bx = blockIdx.x, tid = threadIdx.x;
    if (bx < 64) {
        int idx = bx * 256 + tid;          // 16384 = 64 n x 256 k
        int n = idx >> 8, k = idx & 255;
        float sc = bn1[n] * rsqrtf(bn1[192 + n] + BN_EPS);
        ((u16*)(ws + OFF_WTBF))[idx] = f2bf(w1[n * C_IN + k] * sc);
    } else {
        if (tid < 64) {
            float sc = bn1[tid] * rsqrtf(bn1[192 + tid] + BN_EPS);
            ws[OFF_BIASA + tid] = bn1[64 + tid] - bn1[128 + tid] * sc;
        }
        if (tid < 8) {
            float s = 0.f;
            for (int p = 0; p < 64; ++p) { float v = protos[tid * 64 + p]; s += v * v; }
            ws[OFF_PNORM + tid] = s;
        }
        if (tid < 4) {
            unsigned* mm = (unsigned*)(ws + OFF_MINMAX);
            mm[tid * 2]     = 0x7f7fffffu;
            mm[tid * 2 + 1] = 0u;
        }
    }
}

// ---------------- A: 1x1 conv (256->64) + BN + SiLU via bf16 MFMA -------------
// Block = 1 row (128 px) x 64 out. 4 waves; wave w: pixels [w*32, w*32+32).
// K=256 in 8 chunks of 32, double-buffered LDS, x converted fp32->bf16 on stage.
#define LDA 36    // bf16 per pixel row (18-bank stride: conflict-free frag reads)
#define LDB 264   // bf16 per n row (16B-aligned, 2-way only)
__global__ __launch_bounds__(256) void conv1x1_kernel(
    const float* __restrict__ x, const u16* __restrict__ wtb,
    const float* __restrict__ bias, u16* __restrict__ h)
{
    __shared__ u16 As[2][128 * LDA];   // 18432 B
    __shared__ u16 Bs[64 * LDB];       // 33792 B
    int bx = blockIdx.x;
    int img = bx >> 7, row = bx & 127;
    int tid = threadIdx.x;
    int wid = tid >> 6, lane = tid & 63;
    int mm = lane & 15, kb = lane >> 4;

    // stage B once: thread t -> n = t>>2, k-quarter (t&3)*64
    {
        int n = tid >> 2, k0 = (tid & 3) * 64;
        const u16* src = wtb + n * 256 + k0;
        u16* dst = Bs + n * LDB + k0;
#pragma unroll
        for (int i = 0; i < 64; i += 4)
            *(ushort4*)(dst + i) = *(const ushort4*)(src + i);
    }

    // A staging: cp = tid>>4 -> channels {2cp,2cp+1}; pg = tid&15 -> px pg+16i
    int cp = tid >> 4, pg = tid & 15;
    const float* xbase = x + (size_t)img * C_IN * HW + row * W_IMG;
    {
        const float* xc0 = xbase + (size_t)(2 * cp) * HW;
        const float* xc1 = xc0 + HW;
#pragma unroll
        for (int i = 0; i < 8; ++i) {
            int px = pg + 16 * i;
            ushort2 pk; pk.x = f2bf(xc0[px]); pk.y = f2bf(xc1[px]);
            *(ushort2*)(&As[0][px * LDA + 2 * cp]) = pk;
        }
    }
    __syncthreads();

    f32x4 acc[2][4];
#pragma unroll
    for (int mt = 0; mt < 2; ++mt)
#pragma unroll
        for (int nt = 0; nt < 4; ++nt) acc[mt][nt] = (f32x4){0.f, 0.f, 0.f, 0.f};

    for (int k = 0; k < 8; ++k) {
        float p0[8], p1[8];
        if (k < 7) {
            const float* xc0 = xbase + (size_t)((k + 1) * 32 + 2 * cp) * HW;
            const float* xc1 = xc0 + HW;
#pragma unroll
            for (int i = 0; i < 8; ++i) {
                int px = pg + 16 * i;
                p0[i] = xc0[px]; p1[i] = xc1[px];
            }
        }

        const u16* Ab = As[k & 1];
        bf16x8 afrag[2], bfrag[4];
#pragma unroll
        for (int mt = 0; mt < 2; ++mt) {
            const u16* ap = Ab + (wid * 32 + mt * 16 + mm) * LDA + kb * 8;
            bf16x4 lo = *(const bf16x4*)ap;
            bf16x4 hi = *(const bf16x4*)(ap + 4);
            afrag[mt] = __builtin_shufflevector(lo, hi, 0, 1, 2, 3, 4, 5, 6, 7);
        }
#pragma unroll
        for (int nt = 0; nt < 4; ++nt)
            bfrag[nt] = *(const bf16x8*)(Bs + (nt * 16 + mm) * LDB + k * 32 + kb * 8);
#pragma unroll
        for (int mt = 0; mt < 2; ++mt)
#pragma unroll
            for (int nt = 0; nt < 4; ++nt)
                acc[mt][nt] = __builtin_amdgcn_mfma_f32_16x16x32_bf16(
                    afrag[mt], bfrag[nt], acc[mt][nt], 0, 0, 0);

        if (k < 7) {
            u16* An = As[(k + 1) & 1];
#pragma unroll
            for (int i = 0; i < 8; ++i) {
                int px = pg + 16 * i;
                ushort2 pk; pk.x = f2bf(p0[i]); pk.y = f2bf(p1[i]);
                *(ushort2*)(&An[px * LDA + 2 * cp]) = pk;
            }
        }
        __syncthreads();
    }

    // epilogue: D row = pixel = (lane>>4)*4+reg, col = n = lane&15
#pragma unroll
    for (int mt = 0; mt < 2; ++mt) {
        int pxb = wid * 32 + mt * 16 + kb * 4;
#pragma unroll
        for (int nt = 0; nt < 4; ++nt) {
            int n = nt * 16 + mm;
            float bb = bias[n];
            ushort4 o;
            o.x = f2bf(silu_f(acc[mt][nt][0] + bb));
            o.y = f2bf(silu_f(acc[mt][nt][1] + bb));
            o.z = f2bf(silu_f(acc[mt][nt][2] + bb));
            o.w = f2bf(silu_f(acc[mt][nt][3] + bb));
            *(ushort4*)(h + ((size_t)img * P_CH + n) * HW + row * W_IMG + pxb) = o;
        }
    }
}

// ---------------- B: DW3x3 + BN + SiLU fused with proto-distance (bf16 in) ---
__global__ __launch_bounds__(1024) void dwconv_dev_kernel(
    const u16* __restrict__ h, const float* __restrict__ dw,
    const float* __restrict__ bn2, const float* __restrict__ protos,
    const float* __restrict__ pnorm, float* __restrict__ md,
    unsigned* __restrict__ minmax)
{
    __shared__ float smem[4 * 8 * 324];
    int img = blockIdx.x >> 6;
    int t = blockIdx.x & 63;
    int y0 = (t >> 3) << 4, x0 = (t & 7) << 4;
    int tid = threadIdx.x;
    int q = tid >> 8;
    int qtid = tid & 255;
    int ty = qtid >> 4, tx = qtid & 15;

    const u16* himg = h + (size_t)img * P_CH * HW;
    float* qt = smem + q * (8 * 324);

    int  pre_off[11];
    bool pre_ok[11];
    bool pre_v[11];
#pragma unroll
    for (int r = 0; r < 11; ++r) {
        int l = qtid + r * 256;
        bool valid = l < 2592;
        int cl = l / 324;
        int rr = l - cl * 324;
        int ly = rr / 18, lx = rr - ly * 18;
        int yy = y0 - 1 + ly, xx = x0 - 1 + lx;
        bool inb = (yy >= 0) & (yy < H_IMG) & (xx >= 0) & (xx < W_IMG);
        pre_v[r] = valid;
        pre_ok[r] = valid && inb;
        pre_off[r] = cl * HW + (inb ? (yy * W_IMG + xx) : 0);
    }

    float norm2 = 0.f;
    float dot[K_PROTO];
#pragma unroll
    for (int k = 0; k < K_PROTO; ++k) dot[k] = 0.f;

    {
        const u16* hs = himg + (size_t)(q * 16) * HW;
#pragma unroll
        for (int r = 0; r < 11; ++r) {
            float v = pre_ok[r] ? bf2f(hs[pre_off[r]]) : 0.f;
            if (pre_v[r]) qt[qtid + r * 256] = v;
        }
    }
    __syncthreads();

    for (int k = 0; k < 2; ++k) {
        float pf[11];
        if (k == 0) {
            const u16* hs = himg + (size_t)(q * 16 + 8) * HW;
#pragma unroll
            for (int r = 0; r < 11; ++r)
                pf[r] = pre_ok[r] ? bf2f(hs[pre_off[r]]) : 0.f;
        }

        int c0 = q * 16 + k * 8;
#pragma unroll
        for (int cl = 0; cl < 8; ++cl) {
            int ch = c0 + cl;
            const float* tc = qt + cl * 324;
            const float* wch = dw + ch * 9;
            float s = 0.f;
#pragma unroll
            for (int dy = 0; dy < 3; ++dy)
#pragma unroll
                for (int dx = 0; dx < 3; ++dx)
                    s = fmaf(tc[(ty + dy) * 18 + tx + dx], wch[dy * 3 + dx], s);
            float g = bn2[ch], bb = bn2[64 + ch], m = bn2[128 + ch], vv = bn2[192 + ch];
            float scale = g * rsqrtf(vv + BN_EPS);
            float val = silu_f(scale * s + (bb - m * scale));
            norm2 = fmaf(val, val, norm2);
#pragma unroll
            for (int kk = 0; kk < K_PROTO; ++kk)
                dot[kk] = fmaf(val, protos[kk * 64 + ch], dot[kk]);
        }

        if (k == 0) {
            __syncthreads();
#pragma unroll
            for (int r = 0; r < 11; ++r)
                if (pre_v[r]) qt[qtid + r * 256] = pf[r];
            __syncthreads();
        }
    }
    __syncthreads();

    float* P = smem;
    {
        float* dst = P + (q * 256 + qtid) * 9;
        dst[0] = norm2;
#pragma unroll
        for (int kk = 0; kk < K_PROTO; ++kk) dst[1 + kk] = dot[kk];
    }
    __syncthreads();

    float wmin = 1e30f, wmax = -1e30f, mdv = 0.f;
    if (q == 0) {
        float n2 = 0.f, dd[K_PROTO];
#pragma unroll
        for (int kk = 0; kk < K_PROTO; ++kk) dd[kk] = 0.f;
#pragma unroll
        for (int qq = 0; qq < 4; ++qq) {
            const float* src = P + (qq * 256 + qtid) * 9;
            n2 += src[0];
#pragma unroll
            for (int kk = 0; kk < K_PROTO; ++kk) dd[kk] += src[1 + kk];
        }
        float d2min = 1e30f;
#pragma unroll
        for (int kk = 0; kk < K_PROTO; ++kk)
            d2min = fminf(d2min, n2 + pnorm[kk] - 2.f * dd[kk]);
        mdv = sqrtf(fmaxf(d2min, 0.f)) * (1.f / 1.000001f);
        md[img * HW + (y0 + ty) * W_IMG + (x0 + tx)] = mdv;
        wmin = mdv; wmax = mdv;
#pragma unroll
        for (int d = 32; d > 0; d >>= 1) {
            wmin = fminf(wmin, __shfl_xor(wmin, d));
            wmax = fmaxf(wmax, __shfl_xor(wmax, d));
        }
    }
    __syncthreads();
    if (q == 0 && (qtid & 63) == 0) {
        int wid = qtid >> 6;
        smem[wid * 2]     = wmin;
        smem[wid * 2 + 1] = wmax;
    }
    __syncthreads();
    if (tid == 0) {
        float bmin = fminf(fminf(smem[0], smem[2]), fminf(smem[4], smem[6]));
        float bmax = fmaxf(fmaxf(smem[1], smem[3]), fmaxf(smem[5], smem[7]));
        atomicMin(&minmax[img * 2],     __float_as_uint(bmin));
        atomicMax(&minmax[img * 2 + 1], __float_as_uint(bmax));
    }
}

// ---------------- C: normalize deviation + dual DS-conv attention ------------
__global__ __launch_bounds__(256) void attn_kernel(
    const float* __restrict__ md, const unsigned* __restrict__ minmax,
    const float* __restrict__ bs_dw, const float* __restrict__ bs_bn1,
    const float* __restrict__ bs_pw, const float* __restrict__ bs_bn2,
    const float* __restrict__ bl_dw, const float* __restrict__ bl_bn1,
    const float* __restrict__ bl_pw, const float* __restrict__ bl_bn2,
    const float* __restrict__ fuse_w, const float* __restrict__ fuse_b,
    float* __restrict__ attn)
{
    __shared__ float tile[20 * 20];
    int img = blockIdx.x >> 6;
    int t = blockIdx.x & 63;
    int y0 = (t >> 3) << 4, x0 = (t & 7) << 4;
    int tid = threadIdx.x;
    int ty = tid >> 4, tx = tid & 15;

    float fdmin = __uint_as_float(minmax[img * 2]);
    float fdmax = __uint_as_float(minmax[img * 2 + 1]);
    float inv = 1.f / (fdmax - fdmin + 1e-6f);

    const float* mdi = md + img * HW;
    for (int l = tid; l < 400; l += 256) {
        int ly = l / 20, lx = l - ly * 20;
        int yy = y0 - 2 + ly, xx = x0 - 2 + lx;
        float v = 0.f;
        if (yy >= 0 && yy < H_IMG && xx >= 0 && xx < W_IMG)
            v = (mdi[yy * W_IMG + xx] - fdmin) * inv;
        tile[l] = v;
    }
    __syncthreads();

    float c3 = 0.f;
#pragma unroll
    for (int dy = 0; dy < 3; ++dy)
#pragma unroll
        for (int dx = 0; dx < 3; ++dx)
            c3 = fmaf(tile[(ty + 1 + dy) * 20 + tx + 1 + dx], bs_dw[dy * 3 + dx], c3);
    float c5 = 0.f;
#pragma unroll
    for (int dy = 0; dy < 5; ++dy)
#pragma unroll
        for (int dx = 0; dx < 5; ++dx)
            c5 = fmaf(tile[(ty + dy) * 20 + tx + dx], bl_dw[dy * 5 + dx], c5);

    float s1 = bs_bn1[0] * rsqrtf(bs_bn1[3] + BN_EPS);
    float t1 = silu_f(s1 * c3 + (bs_bn1[1] - bs_bn1[2] * s1));
    float s2 = bl_bn1[0] * rsqrtf(bl_bn1[3] + BN_EPS);
    float t2 = silu_f(s2 * c5 + (bl_bn1[1] - bl_bn1[2] * s2));

    float acc = fuse_b[0];
#pragma unroll
    for (int c = 0; c < 8; ++c) {
        float scs = bs_bn2[c] * rsqrtf(bs_bn2[24 + c] + BN_EPS);
        float u1 = silu_f(scs * (bs_pw[c] * t1) + (bs_bn2[8 + c] - bs_bn2[16 + c] * scs));
        acc = fmaf(fuse_w[c], u1, acc);
        float scl = bl_bn2[c] * rsqrtf(bl_bn2[24 + c] + BN_EPS);
        float u2 = silu_f(scl * (bl_pw[c] * t2) + (bl_bn2[8 + c] - bl_bn2[16 + c] * scl));
        acc = fmaf(fuse_w[8 + c], u2, acc);
    }
    float a = 1.f / (1.f + __expf(-acc));
    attn[img * HW + (y0 + ty) * W_IMG + (x0 + tx)] = a;
}

// ---------------- D: out = x * (1 + gamma * attn) ----------------------------
__global__ __launch_bounds__(256) void final_kernel(
    const float* __restrict__ x, const float* __restrict__ attn,
    const float* __restrict__ gamma, float* __restrict__ out)
{
    size_t i = ((size_t)blockIdx.x * 256 + (size_t)threadIdx.x) * 4;
    float g = gamma[0];
    int b = (int)(i / ((size_t)C_IN * HW));
    int hw = (int)(i % HW);
    const float4 xv = *(const float4*)(x + i);
    const float4 av = *(const float4*)(attn + (size_t)b * HW + hw);
    float4 o;
    o.x = xv.x * (1.f + g * av.x);
    o.y = xv.y * (1.f + g * av.y);
    o.z = xv.z * (1.f + g * av.z);
    o.w = xv.w * (1.f + g * av.w);
    *(float4*)(out + i) = o;
}

extern "C" void kernel_launch(void* const* d_in, const int* in_sizes, int n_in,
                              void* d_out, int out_size, void* d_ws, size_t ws_size,
                              hipStream_t stream) {
    const float* x      = (const float*)d_in[0];
    const float* fp_w1  = (const float*)d_in[1];
    const float* fp_bn1 = (const float*)d_in[2];
    const float* fp_dw  = (const float*)d_in[3];
    const float* fp_bn2 = (const float*)d_in[4];
    const float* protos = (const float*)d_in[5];
    const float* bs_dw  = (const float*)d_in[6];
    const float* bs_bn1 = (const float*)d_in[7];
    const float* bs_pw  = (const float*)d_in[8];
    const float* bs_bn2 = (const float*)d_in[9];
    const float* bl_dw  = (const float*)d_in[10];
    const float* bl_bn1 = (const float*)d_in[11];
    const float* bl_pw  = (const float*)d_in[12];
    const float* bl_bn2 = (const float*)d_in[13];
    const float* fuse_w = (const float*)d_in[14];
    const float* fuse_b = (const float*)d_in[15];
    const float* gamma  = (const float*)d_in[16];
    float* ws  = (float*)d_ws;
    float* out = (float*)d_out;

    prep_kernel<<<65, 256, 0, stream>>>(fp_w1, fp_bn1, protos, ws);
    conv1x1_kernel<<<512, 256, 0, stream>>>(x, (const u16*)(ws + OFF_WTBF),
                                            ws + OFF_BIASA, (u16*)(ws + OFF_H));
    dwconv_dev_kernel<<<256, 1024, 0, stream>>>((const u16*)(ws + OFF_H), fp_dw, fp_bn2,
                                                protos, ws + OFF_PNORM, ws + OFF_MD,
                                                (unsigned*)(ws + OFF_MINMAX));
    attn_kernel<<<256, 256, 0, stream>>>(ws + OFF_MD, (const unsigned*)(ws + OFF_MINMAX),
                                         bs_dw, bs_bn1, bs_pw, bs_bn2,
                                         bl_dw, bl_bn1, bl_pw, bl_bn2,
                                         fuse_w, fuse_b, ws + OFF_ATTN);
    final_kernel<<<16384, 256, 0, stream>>>(x, ws + OFF_ATTN, gamma, out);
}